// Round 3
// baseline (810.367 us; speedup 1.0000x reference)
//
#include <hip/hip_runtime.h>

typedef unsigned short u16;
typedef __attribute__((ext_vector_type(8))) short bf16x8;
typedef __attribute__((ext_vector_type(4))) float f32x4;

__device__ inline u16 f2bf(float f){
  union { float f; unsigned u; } v; v.f = f;
  unsigned r = v.u + 0x7FFFu + ((v.u >> 16) & 1u);
  return (u16)(r >> 16);
}
__device__ inline float bf2f(u16 u){
  union { unsigned u; float f; } v; v.u = ((unsigned)u) << 16;
  return v.f;
}

// ---------------- prep: split z (fp32 -> bf16 hi/lo) ----------------
__global__ __launch_bounds__(256) void split_f32(const float* __restrict__ x,
                                                 u16* __restrict__ hi,
                                                 u16* __restrict__ lo, int n4){
  int i = blockIdx.x * 256 + threadIdx.x;
  if (i >= n4) return;
  float4 v = ((const float4*)x)[i];
  float a0 = v.x, a1 = v.y, a2 = v.z, a3 = v.w;
  u16 h0 = f2bf(a0), h1 = f2bf(a1), h2 = f2bf(a2), h3 = f2bf(a3);
  ushort4 h; h.x = h0; h.y = h1; h.z = h2; h.w = h3;
  ushort4 l; l.x = f2bf(a0 - bf2f(h0)); l.y = f2bf(a1 - bf2f(h1));
  l.z = f2bf(a2 - bf2f(h2)); l.w = f2bf(a3 - bf2f(h3));
  ((ushort4*)hi)[i] = h;
  ((ushort4*)lo)[i] = l;
}

// ---------------- prep: transpose + split W (1024x1024, [d][n] -> [n][d]) ----------------
__global__ __launch_bounds__(256) void transpose_split_w(
    const float* __restrict__ Wq, const float* __restrict__ Wk, const float* __restrict__ Wv,
    u16* __restrict__ qh, u16* __restrict__ ql,
    u16* __restrict__ kh, u16* __restrict__ kl,
    u16* __restrict__ vh, u16* __restrict__ vl){
  const float* W; u16 *H, *L;
  if (blockIdx.z == 0){ W = Wq; H = qh; L = ql; }
  else if (blockIdx.z == 1){ W = Wk; H = kh; L = kl; }
  else { W = Wv; H = vh; L = vl; }
  __shared__ float t[64][65];
  int d0 = blockIdx.y * 64, n0 = blockIdx.x * 64;
  int tid = threadIdx.x;
  int r = tid >> 4, c4 = (tid & 15) * 4;
  for (int rr = r; rr < 64; rr += 16){
    float4 v = *(const float4*)&W[(size_t)(d0 + rr) * 1024 + n0 + c4];
    t[rr][c4 + 0] = v.x; t[rr][c4 + 1] = v.y; t[rr][c4 + 2] = v.z; t[rr][c4 + 3] = v.w;
  }
  __syncthreads();
  int n = tid >> 4, d4 = (tid & 15) * 4;
  for (int nn = n; nn < 64; nn += 16){
    float x0 = t[d4 + 0][nn], x1 = t[d4 + 1][nn], x2 = t[d4 + 2][nn], x3 = t[d4 + 3][nn];
    u16 h0 = f2bf(x0), h1 = f2bf(x1), h2 = f2bf(x2), h3 = f2bf(x3);
    ushort4 h; h.x = h0; h.y = h1; h.z = h2; h.w = h3;
    ushort4 l; l.x = f2bf(x0 - bf2f(h0)); l.y = f2bf(x1 - bf2f(h1));
    l.z = f2bf(x2 - bf2f(h2)); l.w = f2bf(x3 - bf2f(h3));
    *(ushort4*)&H[(size_t)(n0 + nn) * 1024 + d0 + d4] = h;
    *(ushort4*)&L[(size_t)(n0 + nn) * 1024 + d0 + d4] = l;
  }
}

// ---------------- GEMM: C[M,N] = A[M,K] * B[N,K]^T, bf16 MFMA ----------------
// SPLIT: both operands have hi/lo planes -> 3-MFMA chain (fp32-ish precision).
// EPI: 0 = fp32 C0;  1 = bf16 C0;  2 = split pair (bf16 hi->C0, lo->C1).
// LDS row stride 36 u16 = 72B = 18 banks: conflict-free ds_read_b128
// (lanes 0..15 start-banks {0,18,4,22,...} all distinct; 16B spans tile all
// 32 banks exactly 2x per wave = free per m136).
#define LDSW 36
template<bool SPLIT, int EPI>
__global__ __launch_bounds__(256) void gemm_bt(
    const u16* __restrict__ Ah, const u16* __restrict__ Al, int lda,
    const u16* __restrict__ Bh, const u16* __restrict__ Bl, int ldb,
    void* __restrict__ C0, void* __restrict__ C1, int ldc, int K){
  constexpr int PL = SPLIT ? 2 : 1;
  __shared__ __align__(16) u16 sA[PL * 128 * LDSW];
  __shared__ __align__(16) u16 sB[PL * 128 * LDSW];
  u16* sAh = sA;           u16* sAl = sA + 128 * LDSW * (PL - 1);
  u16* sBh = sB;           u16* sBl = sB + 128 * LDSW * (PL - 1);

  const int tid = threadIdx.x;
  const int lane = tid & 63, wave = tid >> 6;
  const int wr = wave >> 1, wc = wave & 1;
  const int lr = lane & 15, kg = lane >> 4;

  const int m0 = blockIdx.y * 128, n0 = blockIdx.x * 128;
  const int srow = tid >> 1, shalf = tid & 1;
  const int sidx = srow * LDSW + shalf * 16;

  const u16* ga_h = Ah + (size_t)(m0 + srow) * lda + shalf * 16;
  const u16* gb_h = Bh + (size_t)(n0 + srow) * ldb + shalf * 16;
  const u16* ga_l = SPLIT ? (Al + (size_t)(m0 + srow) * lda + shalf * 16) : nullptr;
  const u16* gb_l = SPLIT ? (Bl + (size_t)(n0 + srow) * ldb + shalf * 16) : nullptr;

  uint4 rah0, rah1, rbh0, rbh1;
  uint4 ral0 = {}, ral1 = {}, rbl0 = {}, rbl1 = {};
  rah0 = *(const uint4*)ga_h;       rah1 = *(const uint4*)(ga_h + 8);
  rbh0 = *(const uint4*)gb_h;       rbh1 = *(const uint4*)(gb_h + 8);
  if (SPLIT){
    ral0 = *(const uint4*)ga_l;     ral1 = *(const uint4*)(ga_l + 8);
    rbl0 = *(const uint4*)gb_l;     rbl1 = *(const uint4*)(gb_l + 8);
  }

  f32x4 acc[4][4];
  #pragma unroll
  for (int m = 0; m < 4; m++)
    #pragma unroll
    for (int n = 0; n < 4; n++)
      acc[m][n] = (f32x4){0.f, 0.f, 0.f, 0.f};

  const int KT = K >> 5;
  for (int kt = 0; kt < KT; ++kt){
    __syncthreads();
    *(uint4*)&sAh[sidx] = rah0;     *(uint4*)&sAh[sidx + 8] = rah1;
    *(uint4*)&sBh[sidx] = rbh0;     *(uint4*)&sBh[sidx + 8] = rbh1;
    if (SPLIT){
      *(uint4*)&sAl[sidx] = ral0;   *(uint4*)&sAl[sidx + 8] = ral1;
      *(uint4*)&sBl[sidx] = rbl0;   *(uint4*)&sBl[sidx + 8] = rbl1;
    }
    __syncthreads();
    if (kt + 1 < KT){
      ga_h += 32; gb_h += 32;
      rah0 = *(const uint4*)ga_h;   rah1 = *(const uint4*)(ga_h + 8);
      rbh0 = *(const uint4*)gb_h;   rbh1 = *(const uint4*)(gb_h + 8);
      if (SPLIT){
        ga_l += 32; gb_l += 32;
        ral0 = *(const uint4*)ga_l; ral1 = *(const uint4*)(ga_l + 8);
        rbl0 = *(const uint4*)gb_l; rbl1 = *(const uint4*)(gb_l + 8);
      }
    }
    bf16x8 afh[4], bfh[4], afl[4], bfl[4];
    #pragma unroll
    for (int m = 0; m < 4; m++){
      int rowa = wr * 64 + m * 16 + lr;
      afh[m] = *(const bf16x8*)&sAh[rowa * LDSW + kg * 8];
      if (SPLIT) afl[m] = *(const bf16x8*)&sAl[rowa * LDSW + kg * 8];
    }
    #pragma unroll
    for (int n = 0; n < 4; n++){
      int rowb = wc * 64 + n * 16 + lr;
      bfh[n] = *(const bf16x8*)&sBh[rowb * LDSW + kg * 8];
      if (SPLIT) bfl[n] = *(const bf16x8*)&sBl[rowb * LDSW + kg * 8];
    }
    #pragma unroll
    for (int m = 0; m < 4; m++)
      #pragma unroll
      for (int n = 0; n < 4; n++){
        acc[m][n] = __builtin_amdgcn_mfma_f32_16x16x32_bf16(afh[m], bfh[n], acc[m][n], 0, 0, 0);
        if (SPLIT){
          acc[m][n] = __builtin_amdgcn_mfma_f32_16x16x32_bf16(afl[m], bfh[n], acc[m][n], 0, 0, 0);
          acc[m][n] = __builtin_amdgcn_mfma_f32_16x16x32_bf16(afh[m], bfl[n], acc[m][n], 0, 0, 0);
        }
      }
  }

  const int row0 = m0 + wr * 64, col0 = n0 + wc * 64 + lr;
  #pragma unroll
  for (int m = 0; m < 4; m++)
    #pragma unroll
    for (int n = 0; n < 4; n++)
      #pragma unroll
      for (int r = 0; r < 4; r++){
        int row = row0 + m * 16 + kg * 4 + r;
        int col = col0 + n * 16;
        float x = acc[m][n][r];
        if (EPI == 0){
          ((float*)C0)[(size_t)row * ldc + col] = x;
        } else if (EPI == 1){
          ((u16*)C0)[(size_t)row * ldc + col] = f2bf(x);
        } else {
          u16 h = f2bf(x);
          ((u16*)C0)[(size_t)row * ldc + col] = h;
          ((u16*)C1)[(size_t)row * ldc + col] = f2bf(x - bf2f(h));
        }
      }
}

// ---------------- softmax over rows of S (4096 fp32), write P bf16 in-place ----------------
// P row i lives in the first 8KB of S row i's 16KB -> P has row stride 8192 u16 elements.
__global__ __launch_bounds__(256) void softmax_rows(float* __restrict__ S){
  int rrow = blockIdx.x;
  float* srow = S + (size_t)rrow * 4096;
  __shared__ float e[4096];
  __shared__ float red[4];
  int tid = threadIdx.x;

  float m = -1e30f;
  for (int i = tid * 4; i < 4096; i += 1024){
    float4 v = *(const float4*)(srow + i);
    m = fmaxf(m, fmaxf(fmaxf(v.x, v.y), fmaxf(v.z, v.w)));
  }
  for (int o = 32; o > 0; o >>= 1) m = fmaxf(m, __shfl_xor(m, o));
  if ((tid & 63) == 0) red[tid >> 6] = m;
  __syncthreads();
  m = fmaxf(fmaxf(red[0], red[1]), fmaxf(red[2], red[3]));

  float s = 0.f;
  for (int i = tid * 4; i < 4096; i += 1024){
    float4 v = *(const float4*)(srow + i);
    float4 ev;
    ev.x = __expf(v.x - m); ev.y = __expf(v.y - m);
    ev.z = __expf(v.z - m); ev.w = __expf(v.w - m);
    s += (ev.x + ev.y) + (ev.z + ev.w);
    *(float4*)&e[i] = ev;
  }
  for (int o = 32; o > 0; o >>= 1) s += __shfl_xor(s, o);
  __syncthreads();               // all reads of srow and red are done
  if ((tid & 63) == 0) red[tid >> 6] = s;
  __syncthreads();
  s = (red[0] + red[1]) + (red[2] + red[3]);

  float scale = 0.03125f / s;    // fold the post-softmax 1/sqrt(dk)=1/32 into P
  u16* prow = (u16*)((char*)S + (size_t)rrow * 16384);
  for (int i = tid * 4; i < 4096; i += 1024){
    float4 v = *(const float4*)&e[i];
    ushort4 o; o.x = f2bf(v.x * scale); o.y = f2bf(v.y * scale);
    o.z = f2bf(v.z * scale); o.w = f2bf(v.w * scale);
    *(ushort4*)(prow + i) = o;
  }
}

extern "C" void kernel_launch(void* const* d_in, const int* in_sizes, int n_in,
                              void* d_out, int out_size, void* d_ws, size_t ws_size,
                              hipStream_t stream){
  const float* z  = (const float*)d_in[0];
  const float* Wq = (const float*)d_in[1];
  const float* Wk = (const float*)d_in[2];
  const float* Wv = (const float*)d_in[3];
  char* ws = (char*)d_ws;
  const size_t MB = 1ull << 20;

  // persistent region (needed through PV): 40MB
  u16* q_hi = (u16*)(ws + 0 * MB);
  u16* q_lo = (u16*)(ws + 8 * MB);
  u16* k_hi = (u16*)(ws + 16 * MB);
  u16* k_lo = (u16*)(ws + 24 * MB);
  u16* v_t  = (u16*)(ws + 32 * MB);   // v^T [1024][4096] bf16
  // S region 40..104MB (64MB). Prep scratch overlaps it (dead before S is written).
  float* S   = (float*)(ws + 40 * MB);
  u16* z_hi  = (u16*)(ws + 40 * MB);
  u16* z_lo  = (u16*)(ws + 48 * MB);
  u16* wqt_h = (u16*)(ws + 56 * MB);
  u16* wqt_l = (u16*)(ws + 58 * MB);
  u16* wkt_h = (u16*)(ws + 60 * MB);
  u16* wkt_l = (u16*)(ws + 62 * MB);
  u16* wvt_h = (u16*)(ws + 64 * MB);
  u16* wvt_l = (u16*)(ws + 66 * MB);

  // prep
  split_f32<<<4096, 256, 0, stream>>>(z, z_hi, z_lo, 4096 * 1024 / 4);
  transpose_split_w<<<dim3(16, 16, 3), 256, 0, stream>>>(Wq, Wk, Wv,
      wqt_h, wqt_l, wkt_h, wkt_l, wvt_h, wvt_l);

  // q = z @ Wq  (split x split, epilogue writes hi/lo pair)   M=4096 N=1024 K=1024
  gemm_bt<true, 2><<<dim3(8, 32), 256, 0, stream>>>(z_hi, z_lo, 1024,
      wqt_h, wqt_l, 1024, q_hi, q_lo, 1024, 1024);
  // k = z @ Wk
  gemm_bt<true, 2><<<dim3(8, 32), 256, 0, stream>>>(z_hi, z_lo, 1024,
      wkt_h, wkt_l, 1024, k_hi, k_lo, 1024, 1024);
  // v^T[n][s] = sum_d Wvt[n][d] * z[s][d]   M=1024 N=4096 K=1024 (plain bf16)
  gemm_bt<false, 1><<<dim3(32, 8), 256, 0, stream>>>(wvt_h, nullptr, 1024,
      z_hi, nullptr, 1024, v_t, nullptr, 4096, 1024);

  // S = q @ k^T  fp32  M=N=4096 K=1024 (split x split)
  gemm_bt<true, 0><<<dim3(32, 32), 256, 0, stream>>>(q_hi, q_lo, 1024,
      k_hi, k_lo, 1024, S, nullptr, 4096, 1024);

  // softmax rows, P bf16 in-place (row stride 8192 u16), scale 1/32 folded in
  softmax_rows<<<4096, 256, 0, stream>>>(S);

  // out = P @ v  (A = P [4096, 4096] lda=8192, B = v^T [1024][4096])  fp32 out
  gemm_bt<false, 0><<<dim3(8, 32), 256, 0, stream>>>((u16*)S, nullptr, 8192,
      v_t, nullptr, 4096, (float*)d_out, nullptr, 1024, 4096);
}

// Round 4
// 252.959 us; speedup vs baseline: 3.2036x; 3.2036x over previous
//
#include <hip/hip_runtime.h>

typedef unsigned short u16;
typedef unsigned int u32;
typedef __attribute__((ext_vector_type(8))) short bf16x8;
typedef __attribute__((ext_vector_type(8))) _Float16 f16x8;
typedef __attribute__((ext_vector_type(4))) float f32x4;

__device__ inline u16 f2bf(float f){
  union { float f; unsigned u; } v; v.f = f;
  unsigned r = v.u + 0x7FFFu + ((v.u >> 16) & 1u);
  return (u16)(r >> 16);
}
__device__ inline float bf2f(u16 u){
  union { unsigned u; float f; } v; v.u = ((unsigned)u) << 16;
  return v.f;
}
__device__ inline u16 f2h(float f){
  union { _Float16 h; u16 u; } v; v.h = (_Float16)f; return v.u;
}

// async 16B/lane global->LDS. lds dest is wave-uniform base + lane*16 (HW).
__device__ inline void gload16(const u16* g, u16* l){
  __builtin_amdgcn_global_load_lds(
      (const __attribute__((address_space(1))) u32*)(const void*)g,
      (__attribute__((address_space(3))) u32*)(void*)l, 16, 0, 0);
}

// ---------------- prep: split z (fp32 -> bf16 hi/lo) ----------------
__global__ __launch_bounds__(256) void split_f32(const float* __restrict__ x,
                                                 u16* __restrict__ hi,
                                                 u16* __restrict__ lo, int n4){
  int i = blockIdx.x * 256 + threadIdx.x;
  if (i >= n4) return;
  float4 v = ((const float4*)x)[i];
  float a0 = v.x, a1 = v.y, a2 = v.z, a3 = v.w;
  u16 h0 = f2bf(a0), h1 = f2bf(a1), h2 = f2bf(a2), h3 = f2bf(a3);
  ushort4 h; h.x = h0; h.y = h1; h.z = h2; h.w = h3;
  ushort4 l; l.x = f2bf(a0 - bf2f(h0)); l.y = f2bf(a1 - bf2f(h1));
  l.z = f2bf(a2 - bf2f(h2)); l.w = f2bf(a3 - bf2f(h3));
  ((ushort4*)hi)[i] = h;
  ((ushort4*)lo)[i] = l;
}

// ---------------- prep: transpose + split W (1024x1024, [d][n] -> [n][d]) ----------------
__global__ __launch_bounds__(256) void transpose_split_w(
    const float* __restrict__ Wq, const float* __restrict__ Wk, const float* __restrict__ Wv,
    u16* __restrict__ qh, u16* __restrict__ ql,
    u16* __restrict__ kh, u16* __restrict__ kl,
    u16* __restrict__ vh, u16* __restrict__ vl){
  const float* W; u16 *H, *L;
  if (blockIdx.z == 0){ W = Wq; H = qh; L = ql; }
  else if (blockIdx.z == 1){ W = Wk; H = kh; L = kl; }
  else { W = Wv; H = vh; L = vl; }
  __shared__ float t[64][65];
  int d0 = blockIdx.y * 64, n0 = blockIdx.x * 64;
  int tid = threadIdx.x;
  int r = tid >> 4, c4 = (tid & 15) * 4;
  for (int rr = r; rr < 64; rr += 16){
    float4 v = *(const float4*)&W[(size_t)(d0 + rr) * 1024 + n0 + c4];
    t[rr][c4 + 0] = v.x; t[rr][c4 + 1] = v.y; t[rr][c4 + 2] = v.z; t[rr][c4 + 3] = v.w;
  }
  __syncthreads();
  int n = tid >> 4, d4 = (tid & 15) * 4;
  for (int nn = n; nn < 64; nn += 16){
    float x0 = t[d4 + 0][nn], x1 = t[d4 + 1][nn], x2 = t[d4 + 2][nn], x3 = t[d4 + 3][nn];
    u16 h0 = f2bf(x0), h1 = f2bf(x1), h2 = f2bf(x2), h3 = f2bf(x3);
    ushort4 h; h.x = h0; h.y = h1; h.z = h2; h.w = h3;
    ushort4 l; l.x = f2bf(x0 - bf2f(h0)); l.y = f2bf(x1 - bf2f(h1));
    l.z = f2bf(x2 - bf2f(h2)); l.w = f2bf(x3 - bf2f(h3));
    *(ushort4*)&H[(size_t)(n0 + nn) * 1024 + d0 + d4] = h;
    *(ushort4*)&L[(size_t)(n0 + nn) * 1024 + d0 + d4] = l;
  }
}

// ---------------- GEMM: C[M,N] = A[M,K] * B[N,K]^T ----------------
// IN: 0 = bf16 split (hi/lo, 3-MFMA chain), 1 = bf16 single, 2 = fp16 single.
// EPI: 0 = fp32, 1 = fp16.
// LDS: linear [128][32] u16 per plane (8KB), double-buffered, staged by
// global_load_lds(16B) with involution chunk-swizzle s = c ^ ((r + r>>2)&3):
// conflict-free ds_read_b128 (8 distinct 4-bank groups x2 per quarter-wave)
// and linear lane*16 HW writes. One __syncthreads per K-tile (drains vmcnt).
template<int IN, int EPI>
__global__ __launch_bounds__(256) void gemm_bt(
    const u16* __restrict__ Ah, const u16* __restrict__ Al, int lda,
    const u16* __restrict__ Bh, const u16* __restrict__ Bl, int ldb,
    void* __restrict__ C0, int ldc, int K){
  constexpr int NPL = (IN == 0) ? 4 : 2;   // planes per buffer
  __shared__ __align__(16) u16 sm[2 * NPL * 4096];

  const int tid = threadIdx.x;
  const int lane = tid & 63, wave = tid >> 6;
  const int wr = wave >> 1, wc = wave & 1;
  const int lr = lane & 15, kg = lane >> 4;
  const int m0 = blockIdx.y * 128, n0 = blockIdx.x * 128;

  // staging lane mapping: lane -> (row l_r in 16-row chunk, 16B slot l_c)
  const int l_r = lane >> 2, l_c = lane & 3;
  const int st_chunk = l_c ^ ((l_r + (l_r >> 2)) & 3);  // global 16B chunk to fetch
  const int rd_swz = (lr + (lr >> 2)) & 3;              // read-side slot swizzle

  f32x4 acc[4][4];
  #pragma unroll
  for (int m = 0; m < 4; m++)
    #pragma unroll
    for (int n = 0; n < 4; n++)
      acc[m][n] = (f32x4){0.f, 0.f, 0.f, 0.f};

  auto STAGE = [&](int buf, int k0){
    #pragma unroll
    for (int c = 0; c < NPL * 8 / 4; ++c){
      int pc = c * 4 + wave;            // wave-uniform plane/chunk id
      int p = pc >> 3, ch = pc & 7;
      const u16* g; int ld, rb;
      if (IN == 0){
        g = (p == 0) ? Ah : (p == 1) ? Al : (p == 2) ? Bh : Bl;
        ld = (p < 2) ? lda : ldb;  rb = (p < 2) ? m0 : n0;
      } else {
        g = (p == 0) ? Ah : Bh;
        ld = (p == 0) ? lda : ldb; rb = (p == 0) ? m0 : n0;
      }
      int r = ch * 16 + l_r;
      const u16* src = g + (size_t)(rb + r) * ld + k0 + st_chunk * 8;
      u16* dst = &sm[((size_t)buf * NPL + p) * 4096 + ch * 512];
      gload16(src, dst);
    }
  };

  const int KT = K >> 5;
  STAGE(0, 0);
  __syncthreads();                      // drains vmcnt(0) + barrier

  for (int kt = 0; kt < KT; ++kt){
    const int buf = kt & 1;
    if (kt + 1 < KT) STAGE(buf ^ 1, (kt + 1) * 32);

    const u16* pA  = &sm[((size_t)buf * NPL + 0) * 4096];
    const u16* pAl = &sm[((size_t)buf * NPL + 1) * 4096];
    const u16* pB  = &sm[((size_t)buf * NPL + (IN == 0 ? 2 : 1)) * 4096];
    const u16* pBl = &sm[((size_t)buf * NPL + 3) * 4096];

    const int slot = (kg ^ rd_swz) * 8;
    bf16x8 afh[4], bfh[4], afl[4], bfl[4];
    f16x8 ah16[4], bh16[4];
    #pragma unroll
    for (int m = 0; m < 4; m++){
      int r = wr * 64 + m * 16 + lr;
      if (IN == 2) ah16[m] = *(const f16x8*)&pA[r * 32 + slot];
      else {
        afh[m] = *(const bf16x8*)&pA[r * 32 + slot];
        if (IN == 0) afl[m] = *(const bf16x8*)&pAl[r * 32 + slot];
      }
    }
    #pragma unroll
    for (int n = 0; n < 4; n++){
      int r = wc * 64 + n * 16 + lr;
      if (IN == 2) bh16[n] = *(const f16x8*)&pB[r * 32 + slot];
      else {
        bfh[n] = *(const bf16x8*)&pB[r * 32 + slot];
        if (IN == 0) bfl[n] = *(const bf16x8*)&pBl[r * 32 + slot];
      }
    }
    #pragma unroll
    for (int m = 0; m < 4; m++)
      #pragma unroll
      for (int n = 0; n < 4; n++){
        if (IN == 2){
          acc[m][n] = __builtin_amdgcn_mfma_f32_16x16x32_f16(ah16[m], bh16[n], acc[m][n], 0, 0, 0);
        } else {
          acc[m][n] = __builtin_amdgcn_mfma_f32_16x16x32_bf16(afh[m], bfh[n], acc[m][n], 0, 0, 0);
          if (IN == 0){
            acc[m][n] = __builtin_amdgcn_mfma_f32_16x16x32_bf16(afl[m], bfh[n], acc[m][n], 0, 0, 0);
            acc[m][n] = __builtin_amdgcn_mfma_f32_16x16x32_bf16(afh[m], bfl[n], acc[m][n], 0, 0, 0);
          }
        }
      }
    __syncthreads();                    // vmcnt(0)+lgkmcnt(0)+barrier: next buf ready
  }

  const int row0 = m0 + wr * 64, col0 = n0 + wc * 64 + lr;
  #pragma unroll
  for (int m = 0; m < 4; m++)
    #pragma unroll
    for (int n = 0; n < 4; n++)
      #pragma unroll
      for (int r = 0; r < 4; r++){
        int row = row0 + m * 16 + kg * 4 + r;
        int col = col0 + n * 16;
        float x = acc[m][n][r];
        if (EPI == 0) ((float*)C0)[(size_t)row * ldc + col] = x;
        else          ((u16*)C0)[(size_t)row * ldc + col] = f2h(x);
      }
}

// ---------------- softmax over rows of S (4096 fp32), write P fp16 in-place ----------------
// P row i lives in the first 8KB of S row i's 16KB -> P row stride 8192 u16.
__global__ __launch_bounds__(256) void softmax_rows(float* __restrict__ S){
  int rrow = blockIdx.x;
  float* srow = S + (size_t)rrow * 4096;
  __shared__ float e[4096];
  __shared__ float red[4];
  int tid = threadIdx.x;

  float m = -1e30f;
  for (int i = tid * 4; i < 4096; i += 1024){
    float4 v = *(const float4*)(srow + i);
    m = fmaxf(m, fmaxf(fmaxf(v.x, v.y), fmaxf(v.z, v.w)));
  }
  for (int o = 32; o > 0; o >>= 1) m = fmaxf(m, __shfl_xor(m, o));
  if ((tid & 63) == 0) red[tid >> 6] = m;
  __syncthreads();
  m = fmaxf(fmaxf(red[0], red[1]), fmaxf(red[2], red[3]));

  float s = 0.f;
  for (int i = tid * 4; i < 4096; i += 1024){
    float4 v = *(const float4*)(srow + i);
    float4 ev;
    ev.x = __expf(v.x - m); ev.y = __expf(v.y - m);
    ev.z = __expf(v.z - m); ev.w = __expf(v.w - m);
    s += (ev.x + ev.y) + (ev.z + ev.w);
    *(float4*)&e[i] = ev;
  }
  for (int o = 32; o > 0; o >>= 1) s += __shfl_xor(s, o);
  __syncthreads();
  if ((tid & 63) == 0) red[tid >> 6] = s;
  __syncthreads();
  s = (red[0] + red[1]) + (red[2] + red[3]);

  float scale = 0.03125f / s;    // fold post-softmax 1/sqrt(dk)=1/32 into P
  u16* prow = (u16*)((char*)S + (size_t)rrow * 16384);
  for (int i = tid * 4; i < 4096; i += 1024){
    float4 v = *(const float4*)&e[i];
    ushort4 o; o.x = f2h(v.x * scale); o.y = f2h(v.y * scale);
    o.z = f2h(v.z * scale); o.w = f2h(v.w * scale);
    *(ushort4*)(prow + i) = o;
  }
}

extern "C" void kernel_launch(void* const* d_in, const int* in_sizes, int n_in,
                              void* d_out, int out_size, void* d_ws, size_t ws_size,
                              hipStream_t stream){
  const float* z  = (const float*)d_in[0];
  const float* Wq = (const float*)d_in[1];
  const float* Wk = (const float*)d_in[2];
  const float* Wv = (const float*)d_in[3];
  char* ws = (char*)d_ws;
  const size_t MB = 1ull << 20;

  // persistent: q16/k16/vt16 (fp16). S fp32 region 24..88MB.
  u16* q16  = (u16*)(ws + 0 * MB);
  u16* k16  = (u16*)(ws + 8 * MB);
  u16* vt16 = (u16*)(ws + 16 * MB);   // v^T [1024][4096] fp16
  float* S  = (float*)(ws + 24 * MB);
  // prep scratch inside S region (dead before S-GEMM writes S):
  u16* z_hi  = (u16*)(ws + 24 * MB);
  u16* z_lo  = (u16*)(ws + 32 * MB);
  u16* wqt_h = (u16*)(ws + 40 * MB);
  u16* wqt_l = (u16*)(ws + 42 * MB);
  u16* wkt_h = (u16*)(ws + 44 * MB);
  u16* wkt_l = (u16*)(ws + 46 * MB);
  u16* wvt_h = (u16*)(ws + 48 * MB);
  u16* wvt_l = (u16*)(ws + 50 * MB);

  split_f32<<<4096, 256, 0, stream>>>(z, z_hi, z_lo, 4096 * 1024 / 4);
  transpose_split_w<<<dim3(16, 16, 3), 256, 0, stream>>>(Wq, Wk, Wv,
      wqt_h, wqt_l, wkt_h, wkt_l, wvt_h, wvt_l);

  // q = z @ Wq (bf16 split in, fp16 out)   M=4096 N=1024 K=1024
  gemm_bt<0, 1><<<dim3(8, 32), 256, 0, stream>>>(z_hi, z_lo, 1024,
      wqt_h, wqt_l, 1024, q16, 1024, 1024);
  // k = z @ Wk
  gemm_bt<0, 1><<<dim3(8, 32), 256, 0, stream>>>(z_hi, z_lo, 1024,
      wkt_h, wkt_l, 1024, k16, 1024, 1024);
  // v^T = Wv^T @ z^T (bf16 single in, fp16 out)  M=1024 N=4096 K=1024
  gemm_bt<1, 1><<<dim3(32, 8), 256, 0, stream>>>(wvt_h, nullptr, 1024,
      z_hi, nullptr, 1024, vt16, 4096, 1024);

  // S = q @ k^T fp32 (fp16 single)  M=N=4096 K=1024
  gemm_bt<2, 0><<<dim3(32, 32), 256, 0, stream>>>(q16, nullptr, 1024,
      k16, nullptr, 1024, S, 4096, 1024);

  // softmax rows -> P fp16 in-place (stride 8192 u16), 1/32 folded in
  softmax_rows<<<4096, 256, 0, stream>>>(S);

  // out = P @ v (fp16 single)  A=P lda=8192, B=v^T ldb=4096; fp32 out
  gemm_bt<2, 0><<<dim3(8, 32), 256, 0, stream>>>((u16*)S, nullptr, 8192,
      vt16, nullptr, 4096, (float*)d_out, 1024, 4096);
}

// Round 5
// 218.609 us; speedup vs baseline: 3.7069x; 1.1571x over previous
//
#include <hip/hip_runtime.h>

typedef unsigned short u16;
typedef unsigned int u32;
typedef __attribute__((ext_vector_type(8))) short bf16x8;
typedef __attribute__((ext_vector_type(8))) _Float16 f16x8;
typedef __attribute__((ext_vector_type(4))) float f32x4;

__device__ inline u16 f2bf(float f){
  union { float f; unsigned u; } v; v.f = f;
  unsigned r = v.u + 0x7FFFu + ((v.u >> 16) & 1u);
  return (u16)(r >> 16);
}
__device__ inline float bf2f(u16 u){
  union { unsigned u; float f; } v; v.u = ((unsigned)u) << 16;
  return v.f;
}
__device__ inline u16 f2h(float f){
  union { _Float16 h; u16 u; } v; v.h = (_Float16)f; return v.u;
}

// async 16B/lane global->LDS. lds dest is wave-uniform base + lane*16 (HW).
__device__ inline void gload16(const u16* g, u16* l){
  __builtin_amdgcn_global_load_lds(
      (const __attribute__((address_space(1))) u32*)(const void*)g,
      (__attribute__((address_space(3))) u32*)(void*)l, 16, 0, 0);
}

// ---------------- prep: split z (fp32 -> bf16 hi/lo) ----------------
__global__ __launch_bounds__(256) void split_f32(const float* __restrict__ x,
                                                 u16* __restrict__ hi,
                                                 u16* __restrict__ lo, int n4){
  int i = blockIdx.x * 256 + threadIdx.x;
  if (i >= n4) return;
  float4 v = ((const float4*)x)[i];
  float a0 = v.x, a1 = v.y, a2 = v.z, a3 = v.w;
  u16 h0 = f2bf(a0), h1 = f2bf(a1), h2 = f2bf(a2), h3 = f2bf(a3);
  ushort4 h; h.x = h0; h.y = h1; h.z = h2; h.w = h3;
  ushort4 l; l.x = f2bf(a0 - bf2f(h0)); l.y = f2bf(a1 - bf2f(h1));
  l.z = f2bf(a2 - bf2f(h2)); l.w = f2bf(a3 - bf2f(h3));
  ((ushort4*)hi)[i] = h;
  ((ushort4*)lo)[i] = l;
}

// ---------------- prep: transpose + split W (1024x1024, [d][n] -> [n][d]) ----------------
__global__ __launch_bounds__(256) void transpose_split_w(
    const float* __restrict__ Wq, const float* __restrict__ Wk, const float* __restrict__ Wv,
    u16* __restrict__ qh, u16* __restrict__ ql,
    u16* __restrict__ kh, u16* __restrict__ kl,
    u16* __restrict__ vh, u16* __restrict__ vl){
  const float* W; u16 *H, *L;
  if (blockIdx.z == 0){ W = Wq; H = qh; L = ql; }
  else if (blockIdx.z == 1){ W = Wk; H = kh; L = kl; }
  else { W = Wv; H = vh; L = vl; }
  __shared__ float t[64][65];
  int d0 = blockIdx.y * 64, n0 = blockIdx.x * 64;
  int tid = threadIdx.x;
  int r = tid >> 4, c4 = (tid & 15) * 4;
  for (int rr = r; rr < 64; rr += 16){
    float4 v = *(const float4*)&W[(size_t)(d0 + rr) * 1024 + n0 + c4];
    t[rr][c4 + 0] = v.x; t[rr][c4 + 1] = v.y; t[rr][c4 + 2] = v.z; t[rr][c4 + 3] = v.w;
  }
  __syncthreads();
  int n = tid >> 4, d4 = (tid & 15) * 4;
  for (int nn = n; nn < 64; nn += 16){
    float x0 = t[d4 + 0][nn], x1 = t[d4 + 1][nn], x2 = t[d4 + 2][nn], x3 = t[d4 + 3][nn];
    u16 h0 = f2bf(x0), h1 = f2bf(x1), h2 = f2bf(x2), h3 = f2bf(x3);
    ushort4 h; h.x = h0; h.y = h1; h.z = h2; h.w = h3;
    ushort4 l; l.x = f2bf(x0 - bf2f(h0)); l.y = f2bf(x1 - bf2f(h1));
    l.z = f2bf(x2 - bf2f(h2)); l.w = f2bf(x3 - bf2f(h3));
    *(ushort4*)&H[(size_t)(n0 + nn) * 1024 + d0 + d4] = h;
    *(ushort4*)&L[(size_t)(n0 + nn) * 1024 + d0 + d4] = l;
  }
}

// ---------------- GEMM: C[M,N] = A[M,K] * B[N,K]^T ----------------
// IN: 0 = bf16 split (hi/lo, 3-MFMA chain), 1 = bf16 single, 2 = fp16 single.
// EPI: 0 = fp32, 1 = fp16.
// LDS [128][32] u16/plane, double-buffered, staged via global_load_lds(16B)
// with involution chunk-swizzle (conflict-free ds_read_b128, linear HW writes).
// K-loop: counted vmcnt (T4) -- tile t+1's loads stay in flight across the
// whole iteration; barrier-1 (after vmcnt(L)) publishes tile t, barrier-2
// protects the buffer being re-staged. asm memory fences pin LDS ops.
template<int IN, int EPI>
__global__ __launch_bounds__(256) void gemm_bt(
    const u16* __restrict__ Ah, const u16* __restrict__ Al, int lda,
    const u16* __restrict__ Bh, const u16* __restrict__ Bl, int ldb,
    void* __restrict__ C0, int ldc, int K){
  constexpr int NPL = (IN == 0) ? 4 : 2;   // planes per buffer
  __shared__ __align__(16) u16 sm[2 * NPL * 4096];

  const int tid = threadIdx.x;
  const int lane = tid & 63, wave = tid >> 6;
  const int wr = wave >> 1, wc = wave & 1;
  const int lr = lane & 15, kg = lane >> 4;

  // bijective XCD swizzle (all our grids have nwg % 8 == 0)
  const int nwg = gridDim.x * gridDim.y;
  const int id = blockIdx.y * gridDim.x + blockIdx.x;
  const int chunk = nwg >> 3;
  const int swz = (id & 7) * chunk + (id >> 3);
  const int bx = swz % gridDim.x, by = swz / gridDim.x;
  const int m0 = by * 128, n0 = bx * 128;

  // staging lane mapping: lane -> (row l_r in 16-row chunk, 16B slot l_c)
  const int l_r = lane >> 2, l_c = lane & 3;
  const int st_chunk = l_c ^ ((l_r + (l_r >> 2)) & 3);  // global 16B chunk to fetch
  const int rd_swz = (lr + (lr >> 2)) & 3;              // read-side slot swizzle

  f32x4 acc[4][4];
  #pragma unroll
  for (int m = 0; m < 4; m++)
    #pragma unroll
    for (int n = 0; n < 4; n++)
      acc[m][n] = (f32x4){0.f, 0.f, 0.f, 0.f};

  auto STAGE = [&](int buf, int k0){
    #pragma unroll
    for (int c = 0; c < NPL * 8 / 4; ++c){
      int pc = c * 4 + wave;            // wave-uniform plane/chunk id
      int p = pc >> 3, ch = pc & 7;
      const u16* g; int ld, rb;
      if (IN == 0){
        g = (p == 0) ? Ah : (p == 1) ? Al : (p == 2) ? Bh : Bl;
        ld = (p < 2) ? lda : ldb;  rb = (p < 2) ? m0 : n0;
      } else {
        g = (p == 0) ? Ah : Bh;
        ld = (p == 0) ? lda : ldb; rb = (p == 0) ? m0 : n0;
      }
      int r = ch * 16 + l_r;
      const u16* src = g + (size_t)(rb + r) * ld + k0 + st_chunk * 8;
      u16* dst = &sm[((size_t)buf * NPL + p) * 4096 + ch * 512];
      gload16(src, dst);
    }
  };

  const int KT = K >> 5;
  STAGE(0, 0);

  for (int kt = 0; kt < KT; ++kt){
    const int buf = kt & 1;
    if (kt + 1 < KT){
      STAGE(buf ^ 1, (kt + 1) * 32);
      // wait only for tile t's loads (t+1's stay in flight)
      if (IN == 0) asm volatile("s_waitcnt vmcnt(8)" ::: "memory");
      else         asm volatile("s_waitcnt vmcnt(4)" ::: "memory");
    } else {
      asm volatile("s_waitcnt vmcnt(0)" ::: "memory");
    }
    __builtin_amdgcn_s_barrier();           // barrier-1: tile t published
    asm volatile("" ::: "memory");

    const u16* pA  = &sm[((size_t)buf * NPL + 0) * 4096];
    const u16* pAl = &sm[((size_t)buf * NPL + 1) * 4096];
    const u16* pB  = &sm[((size_t)buf * NPL + (IN == 0 ? 2 : 1)) * 4096];
    const u16* pBl = &sm[((size_t)buf * NPL + 3) * 4096];

    const int slot = (kg ^ rd_swz) * 8;
    bf16x8 afh[4], bfh[4], afl[4], bfl[4];
    f16x8 ah16[4], bh16[4];
    #pragma unroll
    for (int m = 0; m < 4; m++){
      int r = wr * 64 + m * 16 + lr;
      if (IN == 2) ah16[m] = *(const f16x8*)&pA[r * 32 + slot];
      else {
        afh[m] = *(const bf16x8*)&pA[r * 32 + slot];
        if (IN == 0) afl[m] = *(const bf16x8*)&pAl[r * 32 + slot];
      }
    }
    #pragma unroll
    for (int n = 0; n < 4; n++){
      int r = wc * 64 + n * 16 + lr;
      if (IN == 2) bh16[n] = *(const f16x8*)&pB[r * 32 + slot];
      else {
        bfh[n] = *(const bf16x8*)&pB[r * 32 + slot];
        if (IN == 0) bfl[n] = *(const bf16x8*)&pBl[r * 32 + slot];
      }
    }
    #pragma unroll
    for (int m = 0; m < 4; m++)
      #pragma unroll
      for (int n = 0; n < 4; n++){
        if (IN == 2){
          acc[m][n] = __builtin_amdgcn_mfma_f32_16x16x32_f16(ah16[m], bh16[n], acc[m][n], 0, 0, 0);
        } else {
          acc[m][n] = __builtin_amdgcn_mfma_f32_16x16x32_bf16(afh[m], bfh[n], acc[m][n], 0, 0, 0);
          if (IN == 0){
            acc[m][n] = __builtin_amdgcn_mfma_f32_16x16x32_bf16(afl[m], bfh[n], acc[m][n], 0, 0, 0);
            acc[m][n] = __builtin_amdgcn_mfma_f32_16x16x32_bf16(afh[m], bfl[n], acc[m][n], 0, 0, 0);
          }
        }
      }
    asm volatile("" ::: "memory");
    __builtin_amdgcn_s_barrier();           // barrier-2: buf may be re-staged
  }

  const int row0 = m0 + wr * 64, col0 = n0 + wc * 64 + lr;
  #pragma unroll
  for (int m = 0; m < 4; m++)
    #pragma unroll
    for (int n = 0; n < 4; n++)
      #pragma unroll
      for (int r = 0; r < 4; r++){
        int row = row0 + m * 16 + kg * 4 + r;
        int col = col0 + n * 16;
        float x = acc[m][n][r];
        if (EPI == 0) ((float*)C0)[(size_t)row * ldc + col] = x;
        else          ((u16*)C0)[(size_t)row * ldc + col] = f2h(x);
      }
}

// ---------------- softmax over rows of S (4096 fp32), write P fp16 in-place ----------------
// P row i lives in the first 8KB of S row i's 16KB -> P row stride 8192 u16.
__global__ __launch_bounds__(256) void softmax_rows(float* __restrict__ S){
  int rrow = blockIdx.x;
  float* srow = S + (size_t)rrow * 4096;
  __shared__ float e[4096];
  __shared__ float red[4];
  int tid = threadIdx.x;

  float m = -1e30f;
  for (int i = tid * 4; i < 4096; i += 1024){
    float4 v = *(const float4*)(srow + i);
    m = fmaxf(m, fmaxf(fmaxf(v.x, v.y), fmaxf(v.z, v.w)));
  }
  for (int o = 32; o > 0; o >>= 1) m = fmaxf(m, __shfl_xor(m, o));
  if ((tid & 63) == 0) red[tid >> 6] = m;
  __syncthreads();
  m = fmaxf(fmaxf(red[0], red[1]), fmaxf(red[2], red[3]));

  float s = 0.f;
  for (int i = tid * 4; i < 4096; i += 1024){
    float4 v = *(const float4*)(srow + i);
    float4 ev;
    ev.x = __expf(v.x - m); ev.y = __expf(v.y - m);
    ev.z = __expf(v.z - m); ev.w = __expf(v.w - m);
    s += (ev.x + ev.y) + (ev.z + ev.w);
    *(float4*)&e[i] = ev;
  }
  for (int o = 32; o > 0; o >>= 1) s += __shfl_xor(s, o);
  __syncthreads();
  if ((tid & 63) == 0) red[tid >> 6] = s;
  __syncthreads();
  s = (red[0] + red[1]) + (red[2] + red[3]);

  float scale = 0.03125f / s;    // fold post-softmax 1/sqrt(dk)=1/32 into P
  u16* prow = (u16*)((char*)S + (size_t)rrow * 16384);
  for (int i = tid * 4; i < 4096; i += 1024){
    float4 v = *(const float4*)&e[i];
    ushort4 o; o.x = f2h(v.x * scale); o.y = f2h(v.y * scale);
    o.z = f2h(v.z * scale); o.w = f2h(v.w * scale);
    *(ushort4*)(prow + i) = o;
  }
}

extern "C" void kernel_launch(void* const* d_in, const int* in_sizes, int n_in,
                              void* d_out, int out_size, void* d_ws, size_t ws_size,
                              hipStream_t stream){
  const float* z  = (const float*)d_in[0];
  const float* Wq = (const float*)d_in[1];
  const float* Wk = (const float*)d_in[2];
  const float* Wv = (const float*)d_in[3];
  char* ws = (char*)d_ws;
  const size_t MB = 1ull << 20;

  // persistent: q16/k16/vt16 (fp16). S fp32 region 24..88MB.
  u16* q16  = (u16*)(ws + 0 * MB);
  u16* k16  = (u16*)(ws + 8 * MB);
  u16* vt16 = (u16*)(ws + 16 * MB);   // v^T [1024][4096] fp16
  float* S  = (float*)(ws + 24 * MB);
  // prep scratch inside S region (dead before S-GEMM writes S):
  u16* z_hi  = (u16*)(ws + 24 * MB);
  u16* z_lo  = (u16*)(ws + 32 * MB);
  u16* wqt_h = (u16*)(ws + 40 * MB);
  u16* wqt_l = (u16*)(ws + 42 * MB);
  u16* wkt_h = (u16*)(ws + 44 * MB);
  u16* wkt_l = (u16*)(ws + 46 * MB);
  u16* wvt_h = (u16*)(ws + 48 * MB);
  u16* wvt_l = (u16*)(ws + 50 * MB);

  split_f32<<<4096, 256, 0, stream>>>(z, z_hi, z_lo, 4096 * 1024 / 4);
  transpose_split_w<<<dim3(16, 16, 3), 256, 0, stream>>>(Wq, Wk, Wv,
      wqt_h, wqt_l, wkt_h, wkt_l, wvt_h, wvt_l);

  // q = z @ Wq (bf16 split in, fp16 out)   M=4096 N=1024 K=1024
  gemm_bt<0, 1><<<dim3(8, 32), 256, 0, stream>>>(z_hi, z_lo, 1024,
      wqt_h, wqt_l, 1024, q16, 1024, 1024);
  // k = z @ Wk
  gemm_bt<0, 1><<<dim3(8, 32), 256, 0, stream>>>(z_hi, z_lo, 1024,
      wkt_h, wkt_l, 1024, k16, 1024, 1024);
  // v^T = Wv^T @ z^T (bf16 single in, fp16 out)  M=1024 N=4096 K=1024
  gemm_bt<1, 1><<<dim3(32, 8), 256, 0, stream>>>(wvt_h, nullptr, 1024,
      z_hi, nullptr, 1024, vt16, 4096, 1024);

  // S = q @ k^T fp32 (fp16 single)  M=N=4096 K=1024
  gemm_bt<2, 0><<<dim3(32, 32), 256, 0, stream>>>(q16, nullptr, 1024,
      k16, nullptr, 1024, S, 4096, 1024);

  // softmax rows -> P fp16 in-place (stride 8192 u16), 1/32 folded in
  softmax_rows<<<4096, 256, 0, stream>>>(S);

  // out = P @ v (fp16 single)  A=P lda=8192, B=v^T ldb=4096; fp32 out
  gemm_bt<2, 0><<<dim3(8, 32), 256, 0, stream>>>((u16*)S, nullptr, 8192,
      vt16, nullptr, 4096, (float*)d_out, 1024, 4096);
}

// Round 6
// 216.631 us; speedup vs baseline: 3.7408x; 1.0091x over previous
//
#include <hip/hip_runtime.h>

typedef unsigned short u16;
typedef unsigned int u32;
typedef __attribute__((ext_vector_type(8))) short bf16x8;
typedef __attribute__((ext_vector_type(8))) _Float16 f16x8;
typedef __attribute__((ext_vector_type(4))) float f32x4;

__device__ inline u16 f2bf(float f){
  union { float f; unsigned u; } v; v.f = f;
  unsigned r = v.u + 0x7FFFu + ((v.u >> 16) & 1u);
  return (u16)(r >> 16);
}
__device__ inline float bf2f(u16 u){
  union { unsigned u; float f; } v; v.u = ((unsigned)u) << 16;
  return v.f;
}
__device__ inline u16 f2h(float f){
  union { _Float16 h; u16 u; } v; v.h = (_Float16)f; return v.u;
}

// async 16B/lane global->LDS. lds dest is wave-uniform base + lane*16 (HW).
__device__ inline void gload16(const u16* g, u16* l){
  __builtin_amdgcn_global_load_lds(
      (const __attribute__((address_space(1))) u32*)(const void*)g,
      (__attribute__((address_space(3))) u32*)(void*)l, 16, 0, 0);
}

#define WAITV(n) asm volatile("s_waitcnt vmcnt(" #n ")" ::: "memory")

// ---------------- prep: split z (fp32 -> bf16 hi/lo) ----------------
__global__ __launch_bounds__(256) void split_f32(const float* __restrict__ x,
                                                 u16* __restrict__ hi,
                                                 u16* __restrict__ lo, int n4){
  int i = blockIdx.x * 256 + threadIdx.x;
  if (i >= n4) return;
  float4 v = ((const float4*)x)[i];
  float a0 = v.x, a1 = v.y, a2 = v.z, a3 = v.w;
  u16 h0 = f2bf(a0), h1 = f2bf(a1), h2 = f2bf(a2), h3 = f2bf(a3);
  ushort4 h; h.x = h0; h.y = h1; h.z = h2; h.w = h3;
  ushort4 l; l.x = f2bf(a0 - bf2f(h0)); l.y = f2bf(a1 - bf2f(h1));
  l.z = f2bf(a2 - bf2f(h2)); l.w = f2bf(a3 - bf2f(h3));
  ((ushort4*)hi)[i] = h;
  ((ushort4*)lo)[i] = l;
}

// ---------------- prep: transpose + split W (1024x1024, [d][n] -> [n][d]) ----------------
__global__ __launch_bounds__(256) void transpose_split_w(
    const float* __restrict__ Wq, const float* __restrict__ Wk, const float* __restrict__ Wv,
    u16* __restrict__ qh, u16* __restrict__ ql,
    u16* __restrict__ kh, u16* __restrict__ kl,
    u16* __restrict__ vh, u16* __restrict__ vl){
  const float* W; u16 *H, *L;
  if (blockIdx.z == 0){ W = Wq; H = qh; L = ql; }
  else if (blockIdx.z == 1){ W = Wk; H = kh; L = kl; }
  else { W = Wv; H = vh; L = vl; }
  __shared__ float t[64][65];
  int d0 = blockIdx.y * 64, n0 = blockIdx.x * 64;
  int tid = threadIdx.x;
  int r = tid >> 4, c4 = (tid & 15) * 4;
  for (int rr = r; rr < 64; rr += 16){
    float4 v = *(const float4*)&W[(size_t)(d0 + rr) * 1024 + n0 + c4];
    t[rr][c4 + 0] = v.x; t[rr][c4 + 1] = v.y; t[rr][c4 + 2] = v.z; t[rr][c4 + 3] = v.w;
  }
  __syncthreads();
  int n = tid >> 4, d4 = (tid & 15) * 4;
  for (int nn = n; nn < 64; nn += 16){
    float x0 = t[d4 + 0][nn], x1 = t[d4 + 1][nn], x2 = t[d4 + 2][nn], x3 = t[d4 + 3][nn];
    u16 h0 = f2bf(x0), h1 = f2bf(x1), h2 = f2bf(x2), h3 = f2bf(x3);
    ushort4 h; h.x = h0; h.y = h1; h.z = h2; h.w = h3;
    ushort4 l; l.x = f2bf(x0 - bf2f(h0)); l.y = f2bf(x1 - bf2f(h1));
    l.z = f2bf(x2 - bf2f(h2)); l.w = f2bf(x3 - bf2f(h3));
    *(ushort4*)&H[(size_t)(n0 + nn) * 1024 + d0 + d4] = h;
    *(ushort4*)&L[(size_t)(n0 + nn) * 1024 + d0 + d4] = l;
  }
}

// ---------------- GEMM: C[M,N] = A[M,K] * B[N,K]^T ----------------
// IN: 0 = bf16 split (hi/lo, 3-MFMA chain), 1 = bf16 single, 2 = fp16 single.
// EPI: 0 = fp32, 1 = fp16.
// LDS [128][32] u16/plane, staged via global_load_lds(16B) with involution
// chunk-swizzle (conflict-free ds_read_b128, linear HW writes).
// Pipeline: counted vmcnt (T4). Single-plane: DEPTH=2 (triple buffer) so a
// tile's loads get ~2 iterations (~1400cy) to land, covering ~900cy HBM
// latency. Split: DEPTH=1 (compute phase is ~2x longer, covers latency).
template<int IN, int EPI>
__global__ __launch_bounds__(256) void gemm_bt(
    const u16* __restrict__ Ah, const u16* __restrict__ Al, int lda,
    const u16* __restrict__ Bh, const u16* __restrict__ Bl, int ldb,
    void* __restrict__ C0, int ldc, int K){
  constexpr int NPL = (IN == 0) ? 4 : 2;   // planes per buffer
  constexpr int DEPTH = (IN == 0) ? 1 : 2; // prefetch distance
  constexpr int NBUF = DEPTH + 1;
  __shared__ __align__(16) u16 sm[NBUF * NPL * 4096];

  const int tid = threadIdx.x;
  const int lane = tid & 63, wave = tid >> 6;
  const int wr = wave >> 1, wc = wave & 1;
  const int lr = lane & 15, kg = lane >> 4;

  // bijective XCD swizzle (all our grids have nwg % 8 == 0)
  const int nwg = gridDim.x * gridDim.y;
  const int id = blockIdx.y * gridDim.x + blockIdx.x;
  const int chunk = nwg >> 3;
  const int swz = (id & 7) * chunk + (id >> 3);
  const int bx = swz % gridDim.x, by = swz / gridDim.x;
  const int m0 = by * 128, n0 = bx * 128;

  // staging lane mapping: lane -> (row l_r in 16-row chunk, 16B slot l_c)
  const int l_r = lane >> 2, l_c = lane & 3;
  const int st_chunk = l_c ^ ((l_r + (l_r >> 2)) & 3);  // global 16B chunk to fetch
  const int rd_swz = (lr + (lr >> 2)) & 3;              // read-side slot swizzle

  f32x4 acc[4][4];
  #pragma unroll
  for (int m = 0; m < 4; m++)
    #pragma unroll
    for (int n = 0; n < 4; n++)
      acc[m][n] = (f32x4){0.f, 0.f, 0.f, 0.f};

  auto STAGE = [&](int buf, int k0){
    #pragma unroll
    for (int c = 0; c < NPL * 2; ++c){
      int pc = c * 4 + wave;            // wave-uniform plane/chunk id
      int p = pc >> 3, ch = pc & 7;
      const u16* g; int ld, rb;
      if (IN == 0){
        g = (p == 0) ? Ah : (p == 1) ? Al : (p == 2) ? Bh : Bl;
        ld = (p < 2) ? lda : ldb;  rb = (p < 2) ? m0 : n0;
      } else {
        g = (p == 0) ? Ah : Bh;
        ld = (p == 0) ? lda : ldb; rb = (p == 0) ? m0 : n0;
      }
      int r = ch * 16 + l_r;
      const u16* src = g + (size_t)(rb + r) * ld + k0 + st_chunk * 8;
      u16* dst = &sm[((size_t)buf * NPL + p) * 4096 + ch * 512];
      gload16(src, dst);
    }
  };

  const int KT = K >> 5;
  STAGE(0, 0);
  if constexpr (DEPTH == 2){ if (KT > 1) STAGE(1, 32); }

  int bufc = 0, pfb = DEPTH % NBUF;     // kt % NBUF, (kt+DEPTH) % NBUF
  for (int kt = 0; kt < KT; ++kt){
    const int pf = kt + DEPTH;
    if (pf < KT){
      STAGE(pfb, pf * 32);
      WAITV(8);                          // DEPTH batches x L loads in flight
    } else if (kt + 1 < KT){
      if constexpr (IN == 0) WAITV(8); else WAITV(4);
    } else {
      WAITV(0);
    }
    __builtin_amdgcn_s_barrier();        // tile kt published
    asm volatile("" ::: "memory");

    const u16* pA  = &sm[((size_t)bufc * NPL + 0) * 4096];
    const u16* pAl = &sm[((size_t)bufc * NPL + 1) * 4096];
    const u16* pB  = &sm[((size_t)bufc * NPL + (IN == 0 ? 2 : 1)) * 4096];
    const u16* pBl = &sm[((size_t)bufc * NPL + 3) * 4096];

    const int slot = (kg ^ rd_swz) * 8;
    bf16x8 afh[4], bfh[4], afl[4], bfl[4];
    f16x8 ah16[4], bh16[4];
    #pragma unroll
    for (int m = 0; m < 4; m++){
      int r = wr * 64 + m * 16 + lr;
      if (IN == 2) ah16[m] = *(const f16x8*)&pA[r * 32 + slot];
      else {
        afh[m] = *(const bf16x8*)&pA[r * 32 + slot];
        if (IN == 0) afl[m] = *(const bf16x8*)&pAl[r * 32 + slot];
      }
    }
    #pragma unroll
    for (int n = 0; n < 4; n++){
      int r = wc * 64 + n * 16 + lr;
      if (IN == 2) bh16[n] = *(const f16x8*)&pB[r * 32 + slot];
      else {
        bfh[n] = *(const bf16x8*)&pB[r * 32 + slot];
        if (IN == 0) bfl[n] = *(const bf16x8*)&pBl[r * 32 + slot];
      }
    }
    #pragma unroll
    for (int m = 0; m < 4; m++)
      #pragma unroll
      for (int n = 0; n < 4; n++){
        if (IN == 2){
          acc[m][n] = __builtin_amdgcn_mfma_f32_16x16x32_f16(ah16[m], bh16[n], acc[m][n], 0, 0, 0);
        } else {
          acc[m][n] = __builtin_amdgcn_mfma_f32_16x16x32_bf16(afh[m], bfh[n], acc[m][n], 0, 0, 0);
          if (IN == 0){
            acc[m][n] = __builtin_amdgcn_mfma_f32_16x16x32_bf16(afl[m], bfh[n], acc[m][n], 0, 0, 0);
            acc[m][n] = __builtin_amdgcn_mfma_f32_16x16x32_bf16(afh[m], bfl[n], acc[m][n], 0, 0, 0);
          }
        }
      }
    asm volatile("" ::: "memory");
    __builtin_amdgcn_s_barrier();        // buf may be re-staged next iter
    bufc = (bufc + 1 == NBUF) ? 0 : bufc + 1;
    pfb  = (pfb  + 1 == NBUF) ? 0 : pfb  + 1;
  }

  const int row0 = m0 + wr * 64, col0 = n0 + wc * 64 + lr;
  #pragma unroll
  for (int m = 0; m < 4; m++)
    #pragma unroll
    for (int n = 0; n < 4; n++)
      #pragma unroll
      for (int r = 0; r < 4; r++){
        int row = row0 + m * 16 + kg * 4 + r;
        int col = col0 + n * 16;
        float x = acc[m][n][r];
        if (EPI == 0) ((float*)C0)[(size_t)row * ldc + col] = x;
        else          ((u16*)C0)[(size_t)row * ldc + col] = f2h(x);
      }
}

// ---------------- softmax over rows of S (4096 fp32), write P fp16 in-place ----------------
// P row i lives in the first 8KB of S row i's 16KB -> P row stride 8192 u16.
__global__ __launch_bounds__(256) void softmax_rows(float* __restrict__ S){
  int rrow = blockIdx.x;
  float* srow = S + (size_t)rrow * 4096;
  __shared__ float e[4096];
  __shared__ float red[4];
  int tid = threadIdx.x;

  float m = -1e30f;
  for (int i = tid * 4; i < 4096; i += 1024){
    float4 v = *(const float4*)(srow + i);
    m = fmaxf(m, fmaxf(fmaxf(v.x, v.y), fmaxf(v.z, v.w)));
  }
  for (int o = 32; o > 0; o >>= 1) m = fmaxf(m, __shfl_xor(m, o));
  if ((tid & 63) == 0) red[tid >> 6] = m;
  __syncthreads();
  m = fmaxf(fmaxf(red[0], red[1]), fmaxf(red[2], red[3]));

  float s = 0.f;
  for (int i = tid * 4; i < 4096; i += 1024){
    float4 v = *(const float4*)(srow + i);
    float4 ev;
    ev.x = __expf(v.x - m); ev.y = __expf(v.y - m);
    ev.z = __expf(v.z - m); ev.w = __expf(v.w - m);
    s += (ev.x + ev.y) + (ev.z + ev.w);
    *(float4*)&e[i] = ev;
  }
  for (int o = 32; o > 0; o >>= 1) s += __shfl_xor(s, o);
  __syncthreads();
  if ((tid & 63) == 0) red[tid >> 6] = s;
  __syncthreads();
  s = (red[0] + red[1]) + (red[2] + red[3]);

  float scale = 0.03125f / s;    // fold post-softmax 1/sqrt(dk)=1/32 into P
  u16* prow = (u16*)((char*)S + (size_t)rrow * 16384);
  for (int i = tid * 4; i < 4096; i += 1024){
    float4 v = *(const float4*)&e[i];
    ushort4 o; o.x = f2h(v.x * scale); o.y = f2h(v.y * scale);
    o.z = f2h(v.z * scale); o.w = f2h(v.w * scale);
    *(ushort4*)(prow + i) = o;
  }
}

extern "C" void kernel_launch(void* const* d_in, const int* in_sizes, int n_in,
                              void* d_out, int out_size, void* d_ws, size_t ws_size,
                              hipStream_t stream){
  const float* z  = (const float*)d_in[0];
  const float* Wq = (const float*)d_in[1];
  const float* Wk = (const float*)d_in[2];
  const float* Wv = (const float*)d_in[3];
  char* ws = (char*)d_ws;
  const size_t MB = 1ull << 20;

  // persistent: q16/k16/vt16 (fp16). S fp32 region 24..88MB.
  u16* q16  = (u16*)(ws + 0 * MB);
  u16* k16  = (u16*)(ws + 8 * MB);
  u16* vt16 = (u16*)(ws + 16 * MB);   // v^T [1024][4096] fp16
  float* S  = (float*)(ws + 24 * MB);
  // prep scratch inside S region (dead before S-GEMM writes S):
  u16* z_hi  = (u16*)(ws + 24 * MB);
  u16* z_lo  = (u16*)(ws + 32 * MB);
  u16* wqt_h = (u16*)(ws + 40 * MB);
  u16* wqt_l = (u16*)(ws + 42 * MB);
  u16* wkt_h = (u16*)(ws + 44 * MB);
  u16* wkt_l = (u16*)(ws + 46 * MB);
  u16* wvt_h = (u16*)(ws + 48 * MB);
  u16* wvt_l = (u16*)(ws + 50 * MB);

  split_f32<<<4096, 256, 0, stream>>>(z, z_hi, z_lo, 4096 * 1024 / 4);
  transpose_split_w<<<dim3(16, 16, 3), 256, 0, stream>>>(Wq, Wk, Wv,
      wqt_h, wqt_l, wkt_h, wkt_l, wvt_h, wvt_l);

  // q = z @ Wq (bf16 split in, fp16 out)   M=4096 N=1024 K=1024
  gemm_bt<0, 1><<<dim3(8, 32), 256, 0, stream>>>(z_hi, z_lo, 1024,
      wqt_h, wqt_l, 1024, q16, 1024, 1024);
  // k = z @ Wk
  gemm_bt<0, 1><<<dim3(8, 32), 256, 0, stream>>>(z_hi, z_lo, 1024,
      wkt_h, wkt_l, 1024, k16, 1024, 1024);
  // v^T = Wv^T @ z^T (bf16 single in, fp16 out)  M=1024 N=4096 K=1024
  gemm_bt<1, 1><<<dim3(32, 8), 256, 0, stream>>>(wvt_h, nullptr, 1024,
      z_hi, nullptr, 1024, vt16, 4096, 1024);

  // S = q @ k^T fp32 (fp16 single)  M=N=4096 K=1024
  gemm_bt<2, 0><<<dim3(32, 32), 256, 0, stream>>>(q16, nullptr, 1024,
      k16, nullptr, 1024, S, 4096, 1024);

  // softmax rows -> P fp16 in-place (stride 8192 u16), 1/32 folded in
  softmax_rows<<<4096, 256, 0, stream>>>(S);

  // out = P @ v (fp16 single)  A=P lda=8192, B=v^T ldb=4096; fp32 out
  gemm_bt<2, 0><<<dim3(8, 32), 256, 0, stream>>>((u16*)S, nullptr, 8192,
      vt16, nullptr, 4096, (float*)d_out, 1024, 4096);
}

// Round 7
// 208.907 us; speedup vs baseline: 3.8791x; 1.0370x over previous
//
#include <hip/hip_runtime.h>

typedef unsigned short u16;
typedef unsigned int u32;
typedef __attribute__((ext_vector_type(8))) short bf16x8;
typedef __attribute__((ext_vector_type(8))) _Float16 f16x8;
typedef __attribute__((ext_vector_type(4))) float f32x4;

__device__ inline u16 f2bf(float f){
  union { float f; unsigned u; } v; v.f = f;
  unsigned r = v.u + 0x7FFFu + ((v.u >> 16) & 1u);
  return (u16)(r >> 16);
}
__device__ inline float bf2f(u16 u){
  union { unsigned u; float f; } v; v.u = ((unsigned)u) << 16;
  return v.f;
}
__device__ inline u16 f2h(float f){
  union { _Float16 h; u16 u; } v; v.h = (_Float16)f; return v.u;
}

// async 16B/lane global->LDS. lds dest is wave-uniform base + lane*16 (HW).
__device__ inline void gload16(const u16* g, u16* l){
  __builtin_amdgcn_global_load_lds(
      (const __attribute__((address_space(1))) u32*)(const void*)g,
      (__attribute__((address_space(3))) u32*)(void*)l, 16, 0, 0);
}

#define WAITV(n) asm volatile("s_waitcnt vmcnt(" #n ")" ::: "memory")

// ---------------- prep: split z (fp32 -> bf16 hi/lo) ----------------
__global__ __launch_bounds__(256) void split_f32(const float* __restrict__ x,
                                                 u16* __restrict__ hi,
                                                 u16* __restrict__ lo, int n4){
  int i = blockIdx.x * 256 + threadIdx.x;
  if (i >= n4) return;
  float4 v = ((const float4*)x)[i];
  float a0 = v.x, a1 = v.y, a2 = v.z, a3 = v.w;
  u16 h0 = f2bf(a0), h1 = f2bf(a1), h2 = f2bf(a2), h3 = f2bf(a3);
  ushort4 h; h.x = h0; h.y = h1; h.z = h2; h.w = h3;
  ushort4 l; l.x = f2bf(a0 - bf2f(h0)); l.y = f2bf(a1 - bf2f(h1));
  l.z = f2bf(a2 - bf2f(h2)); l.w = f2bf(a3 - bf2f(h3));
  ((ushort4*)hi)[i] = h;
  ((ushort4*)lo)[i] = l;
}

// ---------------- prep: transpose + split W (1024x1024, [d][n] -> [n][d]) ----------------
__global__ __launch_bounds__(256) void transpose_split_w(
    const float* __restrict__ Wq, const float* __restrict__ Wk, const float* __restrict__ Wv,
    u16* __restrict__ qh, u16* __restrict__ ql,
    u16* __restrict__ kh, u16* __restrict__ kl,
    u16* __restrict__ vh, u16* __restrict__ vl){
  const float* W; u16 *H, *L;
  if (blockIdx.z == 0){ W = Wq; H = qh; L = ql; }
  else if (blockIdx.z == 1){ W = Wk; H = kh; L = kl; }
  else { W = Wv; H = vh; L = vl; }
  __shared__ float t[64][65];
  int d0 = blockIdx.y * 64, n0 = blockIdx.x * 64;
  int tid = threadIdx.x;
  int r = tid >> 4, c4 = (tid & 15) * 4;
  for (int rr = r; rr < 64; rr += 16){
    float4 v = *(const float4*)&W[(size_t)(d0 + rr) * 1024 + n0 + c4];
    t[rr][c4 + 0] = v.x; t[rr][c4 + 1] = v.y; t[rr][c4 + 2] = v.z; t[rr][c4 + 3] = v.w;
  }
  __syncthreads();
  int n = tid >> 4, d4 = (tid & 15) * 4;
  for (int nn = n; nn < 64; nn += 16){
    float x0 = t[d4 + 0][nn], x1 = t[d4 + 1][nn], x2 = t[d4 + 2][nn], x3 = t[d4 + 3][nn];
    u16 h0 = f2bf(x0), h1 = f2bf(x1), h2 = f2bf(x2), h3 = f2bf(x3);
    ushort4 h; h.x = h0; h.y = h1; h.z = h2; h.w = h3;
    ushort4 l; l.x = f2bf(x0 - bf2f(h0)); l.y = f2bf(x1 - bf2f(h1));
    l.z = f2bf(x2 - bf2f(h2)); l.w = f2bf(x3 - bf2f(h3));
    *(ushort4*)&H[(size_t)(n0 + nn) * 1024 + d0 + d4] = h;
    *(ushort4*)&L[(size_t)(n0 + nn) * 1024 + d0 + d4] = l;
  }
}

// ---------------- small GEMM (128x128 tile, 4 waves): q,k (split) and v ----
// IN: 0 = bf16 split (hi/lo, 3-MFMA chain), 1 = bf16 single. EPI: 1 = fp16 out.
template<int IN, int EPI>
__global__ __launch_bounds__(256) void gemm_bt(
    const u16* __restrict__ Ah, const u16* __restrict__ Al, int lda,
    const u16* __restrict__ Bh, const u16* __restrict__ Bl, int ldb,
    void* __restrict__ C0, int ldc, int K){
  constexpr int NPL = (IN == 0) ? 4 : 2;
  constexpr int DEPTH = (IN == 0) ? 1 : 2;
  constexpr int NBUF = DEPTH + 1;
  __shared__ __align__(16) u16 sm[NBUF * NPL * 4096];

  const int tid = threadIdx.x;
  const int lane = tid & 63, wave = tid >> 6;
  const int wr = wave >> 1, wc = wave & 1;
  const int lr = lane & 15, kg = lane >> 4;

  const int nwg = gridDim.x * gridDim.y;
  const int id = blockIdx.y * gridDim.x + blockIdx.x;
  const int chunk = nwg >> 3;
  const int swz = (id & 7) * chunk + (id >> 3);
  const int bx = swz % gridDim.x, by = swz / gridDim.x;
  const int m0 = by * 128, n0 = bx * 128;

  const int l_r = lane >> 2, l_c = lane & 3;
  const int st_chunk = l_c ^ ((l_r + (l_r >> 2)) & 3);
  const int rd_swz = (lr + (lr >> 2)) & 3;

  f32x4 acc[4][4];
  #pragma unroll
  for (int m = 0; m < 4; m++)
    #pragma unroll
    for (int n = 0; n < 4; n++)
      acc[m][n] = (f32x4){0.f, 0.f, 0.f, 0.f};

  auto STAGE = [&](int buf, int k0){
    #pragma unroll
    for (int c = 0; c < NPL * 2; ++c){
      int pc = c * 4 + wave;
      int p = pc >> 3, ch = pc & 7;
      const u16* g; int ld, rb;
      if (IN == 0){
        g = (p == 0) ? Ah : (p == 1) ? Al : (p == 2) ? Bh : Bl;
        ld = (p < 2) ? lda : ldb;  rb = (p < 2) ? m0 : n0;
      } else {
        g = (p == 0) ? Ah : Bh;
        ld = (p == 0) ? lda : ldb; rb = (p == 0) ? m0 : n0;
      }
      int r = ch * 16 + l_r;
      const u16* src = g + (size_t)(rb + r) * ld + k0 + st_chunk * 8;
      u16* dst = &sm[((size_t)buf * NPL + p) * 4096 + ch * 512];
      gload16(src, dst);
    }
  };

  const int KT = K >> 5;
  STAGE(0, 0);
  if constexpr (DEPTH == 2){ if (KT > 1) STAGE(1, 32); }

  int bufc = 0, pfb = DEPTH % NBUF;
  for (int kt = 0; kt < KT; ++kt){
    const int pf = kt + DEPTH;
    if (pf < KT){
      STAGE(pfb, pf * 32);
      WAITV(8);
    } else if (kt + 1 < KT){
      if constexpr (IN == 0) WAITV(8); else WAITV(4);
    } else {
      WAITV(0);
    }
    __builtin_amdgcn_s_barrier();
    asm volatile("" ::: "memory");

    const u16* pA  = &sm[((size_t)bufc * NPL + 0) * 4096];
    const u16* pAl = &sm[((size_t)bufc * NPL + 1) * 4096];
    const u16* pB  = &sm[((size_t)bufc * NPL + (IN == 0 ? 2 : 1)) * 4096];
    const u16* pBl = &sm[((size_t)bufc * NPL + 3) * 4096];

    const int slot = (kg ^ rd_swz) * 8;
    bf16x8 afh[4], bfh[4], afl[4], bfl[4];
    #pragma unroll
    for (int m = 0; m < 4; m++){
      int r = wr * 64 + m * 16 + lr;
      afh[m] = *(const bf16x8*)&pA[r * 32 + slot];
      if (IN == 0) afl[m] = *(const bf16x8*)&pAl[r * 32 + slot];
    }
    #pragma unroll
    for (int n = 0; n < 4; n++){
      int r = wc * 64 + n * 16 + lr;
      bfh[n] = *(const bf16x8*)&pB[r * 32 + slot];
      if (IN == 0) bfl[n] = *(const bf16x8*)&pBl[r * 32 + slot];
    }
    #pragma unroll
    for (int m = 0; m < 4; m++)
      #pragma unroll
      for (int n = 0; n < 4; n++){
        acc[m][n] = __builtin_amdgcn_mfma_f32_16x16x32_bf16(afh[m], bfh[n], acc[m][n], 0, 0, 0);
        if (IN == 0){
          acc[m][n] = __builtin_amdgcn_mfma_f32_16x16x32_bf16(afl[m], bfh[n], acc[m][n], 0, 0, 0);
          acc[m][n] = __builtin_amdgcn_mfma_f32_16x16x32_bf16(afh[m], bfl[n], acc[m][n], 0, 0, 0);
        }
      }
    asm volatile("" ::: "memory");
    __builtin_amdgcn_s_barrier();
    bufc = (bufc + 1 == NBUF) ? 0 : bufc + 1;
    pfb  = (pfb  + 1 == NBUF) ? 0 : pfb  + 1;
  }

  const int row0 = m0 + wr * 64, col0 = n0 + wc * 64 + lr;
  #pragma unroll
  for (int m = 0; m < 4; m++)
    #pragma unroll
    for (int n = 0; n < 4; n++)
      #pragma unroll
      for (int r = 0; r < 4; r++){
        int row = row0 + m * 16 + kg * 4 + r;
        int col = col0 + n * 16;
        ((u16*)C0)[(size_t)row * ldc + col] = f2h(acc[m][n][r]);
      }
}

// ---------------- big GEMM: 256x256 tile, 8 waves, wave tile 128x64 --------
// fp16 in, fp32 out. C = A[M,K] * B[N,K]^T over K columns (per z-split).
// 3-buf LDS (96KB), BK=32, 2 phases/tile {2 gloads(t+2) + ds_reads + 16 MFMA},
// one vmcnt(4)+barrier per K-tile (counted, never drains mid-loop). T4+T5.
__global__ __launch_bounds__(512, 2) void gemm256(
    const u16* __restrict__ A, int lda,
    const u16* __restrict__ B, int ldb,
    float* __restrict__ C0z, int l0, float* __restrict__ C1z, int l1,
    float* __restrict__ C2z, int l2, float* __restrict__ C3z, int l3,
    int K){
  __shared__ __align__(16) u16 sm[3 * 16384];   // 3 bufs x (A 8192 + B 8192) u16

  const int tid = threadIdx.x;
  const int lane = tid & 63, wave = tid >> 6;
  const int wr = wave >> 2, wc = wave & 3;        // 2 x 4 waves
  const int lr = lane & 15, kg = lane >> 4;

  const int nwg = gridDim.x * gridDim.y;
  const int id = blockIdx.y * gridDim.x + blockIdx.x;
  const int chunk = nwg >> 3;
  const int swz = (id & 7) * chunk + (id >> 3);
  const int bx = swz % gridDim.x, by = swz / gridDim.x;
  const int m0 = by * 256, n0 = bx * 256;

  A += (size_t)blockIdx.z * (size_t)K;
  B += (size_t)blockIdx.z * (size_t)K;
  float* Cp; int ldc;
  if (blockIdx.z == 0){ Cp = C0z; ldc = l0; }
  else if (blockIdx.z == 1){ Cp = C1z; ldc = l1; }
  else if (blockIdx.z == 2){ Cp = C2z; ldc = l2; }
  else { Cp = C3z; ldc = l3; }

  const int l_r = lane >> 2, l_c = lane & 3;
  const int st_chunk = l_c ^ ((l_r + (l_r >> 2)) & 3);
  const int rd_swz = (lr + (lr >> 2)) & 3;
  const int slot = (kg ^ rd_swz) * 8;

  f32x4 acc[8][4];
  #pragma unroll
  for (int m = 0; m < 8; m++)
    #pragma unroll
    for (int n = 0; n < 4; n++)
      acc[m][n] = (f32x4){0.f, 0.f, 0.f, 0.f};

  // half 0: A chunks (0..15), half 1: B chunks (16..31); 2 gload16/lane/half
  auto STAGE = [&](int buf, int k0, int half){
    #pragma unroll
    for (int c = half * 2; c < half * 2 + 2; ++c){
      int ck = c * 8 + wave;                 // 0..31 across waves
      int p = ck >> 4, ch = ck & 15;
      const u16* g = p ? B : A;
      int ld = p ? ldb : lda;
      int rb = p ? n0 : m0;
      int row = ch * 16 + l_r;
      const u16* src = g + (size_t)(rb + row) * ld + k0 + st_chunk * 8;
      u16* dst = &sm[(size_t)buf * 16384 + p * 8192 + ch * 512];
      gload16(src, dst);
    }
  };

  const int KT = K >> 5;
  STAGE(0, 0, 0); STAGE(0, 0, 1);
  if (KT > 1){ STAGE(1, 32, 0); STAGE(1, 32, 1); }

  int bufc = 0, pfb = 2;
  for (int kt = 0; kt < KT; ++kt){
    if (kt + 1 < KT){ WAITV(4); } else { WAITV(0); }
    __builtin_amdgcn_s_barrier();            // all waves done with buf (kt-1)
    asm volatile("" ::: "memory");

    const u16* pA = &sm[(size_t)bufc * 16384];
    const u16* pB = pA + 8192;
    const bool pf = (kt + 2 < KT);
    const int pk = (kt + 2) * 32;

    // ---- phase 0: stage A(t+2); read B + A[0..3]; MFMA m0-3 ----
    if (pf) STAGE(pfb, pk, 0);
    f16x8 bh[4], ah[4];
    #pragma unroll
    for (int n = 0; n < 4; n++){
      int r = wc * 64 + n * 16 + lr;
      bh[n] = *(const f16x8*)&pB[r * 32 + slot];
    }
    #pragma unroll
    for (int m = 0; m < 4; m++){
      int r = wr * 128 + m * 16 + lr;
      ah[m] = *(const f16x8*)&pA[r * 32 + slot];
    }
    __builtin_amdgcn_s_setprio(1);
    #pragma unroll
    for (int m = 0; m < 4; m++)
      #pragma unroll
      for (int n = 0; n < 4; n++)
        acc[m][n] = __builtin_amdgcn_mfma_f32_16x16x32_f16(ah[m], bh[n], acc[m][n], 0, 0, 0);
    __builtin_amdgcn_s_setprio(0);

    // ---- phase 1: stage B(t+2); read A[4..7]; MFMA m4-7 ----
    if (pf) STAGE(pfb, pk, 1);
    f16x8 ah2[4];
    #pragma unroll
    for (int m = 0; m < 4; m++){
      int r = wr * 128 + (m + 4) * 16 + lr;
      ah2[m] = *(const f16x8*)&pA[r * 32 + slot];
    }
    __builtin_amdgcn_s_setprio(1);
    #pragma unroll
    for (int m = 0; m < 4; m++)
      #pragma unroll
      for (int n = 0; n < 4; n++)
        acc[m + 4][n] = __builtin_amdgcn_mfma_f32_16x16x32_f16(ah2[m], bh[n], acc[m + 4][n], 0, 0, 0);
    __builtin_amdgcn_s_setprio(0);

    asm volatile("" ::: "memory");
    bufc = (bufc + 1 == 3) ? 0 : bufc + 1;
    pfb  = (pfb  + 1 == 3) ? 0 : pfb  + 1;
  }

  const int row0 = m0 + wr * 128, col0 = n0 + wc * 64 + lr;
  #pragma unroll
  for (int m = 0; m < 8; m++)
    #pragma unroll
    for (int n = 0; n < 4; n++)
      #pragma unroll
      for (int r = 0; r < 4; r++){
        int row = row0 + m * 16 + kg * 4 + r;
        int col = col0 + n * 16;
        Cp[(size_t)row * ldc + col] = acc[m][n][r];
      }
}

// ---------------- reduce: out += hole1 + hole2 + slab3 ----------------
__global__ __launch_bounds__(256) void reduce_pv(float* __restrict__ out,
                                                 const float* __restrict__ Sf,
                                                 const float* __restrict__ s3){
  int idx = blockIdx.x * 256 + threadIdx.x;     // over 4096*1024/4 float4
  int r = idx >> 8, c4 = (idx & 255) * 4;
  float4 a = ((const float4*)out)[idx];
  float4 b = ((const float4*)s3)[idx];
  float4 h1 = *(const float4*)&Sf[(size_t)r * 4096 + 2048 + c4];
  float4 h2 = *(const float4*)&Sf[(size_t)r * 4096 + 3072 + c4];
  float4 o;
  o.x = (a.x + b.x) + (h1.x + h2.x);
  o.y = (a.y + b.y) + (h1.y + h2.y);
  o.z = (a.z + b.z) + (h1.z + h2.z);
  o.w = (a.w + b.w) + (h1.w + h2.w);
  ((float4*)out)[idx] = o;
}

// ---------------- softmax over rows of S (4096 fp32), write P fp16 in-place -
// P row i = first 8KB of S row i -> P row stride 8192 u16. Holes (odd 8KB)
// stay untouched and are later used as PV partial slabs.
__global__ __launch_bounds__(256) void softmax_rows(float* __restrict__ S){
  int rrow = blockIdx.x;
  float* srow = S + (size_t)rrow * 4096;
  __shared__ float e[4096];
  __shared__ float red[4];
  int tid = threadIdx.x;

  float m = -1e30f;
  for (int i = tid * 4; i < 4096; i += 1024){
    float4 v = *(const float4*)(srow + i);
    m = fmaxf(m, fmaxf(fmaxf(v.x, v.y), fmaxf(v.z, v.w)));
  }
  for (int o = 32; o > 0; o >>= 1) m = fmaxf(m, __shfl_xor(m, o));
  if ((tid & 63) == 0) red[tid >> 6] = m;
  __syncthreads();
  m = fmaxf(fmaxf(red[0], red[1]), fmaxf(red[2], red[3]));

  float s = 0.f;
  for (int i = tid * 4; i < 4096; i += 1024){
    float4 v = *(const float4*)(srow + i);
    float4 ev;
    ev.x = __expf(v.x - m); ev.y = __expf(v.y - m);
    ev.z = __expf(v.z - m); ev.w = __expf(v.w - m);
    s += (ev.x + ev.y) + (ev.z + ev.w);
    *(float4*)&e[i] = ev;
  }
  for (int o = 32; o > 0; o >>= 1) s += __shfl_xor(s, o);
  __syncthreads();
  if ((tid & 63) == 0) red[tid >> 6] = s;
  __syncthreads();
  s = (red[0] + red[1]) + (red[2] + red[3]);

  float scale = 0.03125f / s;    // fold post-softmax 1/sqrt(dk)=1/32 into P
  u16* prow = (u16*)((char*)S + (size_t)rrow * 16384);
  for (int i = tid * 4; i < 4096; i += 1024){
    float4 v = *(const float4*)&e[i];
    ushort4 o; o.x = f2h(v.x * scale); o.y = f2h(v.y * scale);
    o.z = f2h(v.z * scale); o.w = f2h(v.w * scale);
    *(ushort4*)(prow + i) = o;
  }
}

extern "C" void kernel_launch(void* const* d_in, const int* in_sizes, int n_in,
                              void* d_out, int out_size, void* d_ws, size_t ws_size,
                              hipStream_t stream){
  const float* z  = (const float*)d_in[0];
  const float* Wq = (const float*)d_in[1];
  const float* Wk = (const float*)d_in[2];
  const float* Wv = (const float*)d_in[3];
  char* ws = (char*)d_ws;
  const size_t MB = 1ull << 20;

  // layout: q16 0-8, k16 8-16 (dead after S-GEMM -> PV slab3 at 0-16),
  // vt16 16-24, S fp32 24-88 (P in low 8KB of each row; holes = partials).
  u16* q16  = (u16*)(ws + 0 * MB);
  u16* k16  = (u16*)(ws + 8 * MB);
  u16* vt16 = (u16*)(ws + 16 * MB);
  float* S  = (float*)(ws + 24 * MB);
  float* slab3 = (float*)(ws + 0 * MB);
  // prep scratch inside S region (dead before S-GEMM writes S):
  u16* z_hi  = (u16*)(ws + 24 * MB);
  u16* z_lo  = (u16*)(ws + 32 * MB);
  u16* wqt_h = (u16*)(ws + 40 * MB);
  u16* wqt_l = (u16*)(ws + 42 * MB);
  u16* wkt_h = (u16*)(ws + 44 * MB);
  u16* wkt_l = (u16*)(ws + 46 * MB);
  u16* wvt_h = (u16*)(ws + 48 * MB);
  u16* wvt_l = (u16*)(ws + 50 * MB);

  split_f32<<<4096, 256, 0, stream>>>(z, z_hi, z_lo, 4096 * 1024 / 4);
  transpose_split_w<<<dim3(16, 16, 3), 256, 0, stream>>>(Wq, Wk, Wv,
      wqt_h, wqt_l, wkt_h, wkt_l, wvt_h, wvt_l);

  // q = z @ Wq (bf16 split in, fp16 out)   M=4096 N=1024 K=1024
  gemm_bt<0, 1><<<dim3(8, 32), 256, 0, stream>>>(z_hi, z_lo, 1024,
      wqt_h, wqt_l, 1024, q16, 1024, 1024);
  // k = z @ Wk
  gemm_bt<0, 1><<<dim3(8, 32), 256, 0, stream>>>(z_hi, z_lo, 1024,
      wkt_h, wkt_l, 1024, k16, 1024, 1024);
  // v^T = Wv^T @ z^T (bf16 single in, fp16 out)  M=1024 N=4096 K=1024
  gemm_bt<1, 1><<<dim3(32, 8), 256, 0, stream>>>(wvt_h, nullptr, 1024,
      z_hi, nullptr, 1024, vt16, 4096, 1024);

  // S = q @ k^T fp32  M=N=4096 K=1024 (256^2 kernel, z=1)
  gemm256<<<dim3(16, 16, 1), 512, 0, stream>>>(q16, 1024, k16, 1024,
      S, 4096, S, 4096, S, 4096, S, 4096, 1024);

  // softmax rows -> P fp16 in-place (stride 8192 u16), 1/32 folded in
  softmax_rows<<<4096, 256, 0, stream>>>(S);

  // out = P @ v, split-K=4 (each z: K=1024). A=P lda=8192, B=vt ldb=4096.
  // partials: z0 -> d_out, z1 -> hole1 (S+2048, ldc 4096), z2 -> hole2,
  // z3 -> slab3 (dead q/k region).
  gemm256<<<dim3(4, 16, 4), 512, 0, stream>>>((u16*)S, 8192, vt16, 4096,
      (float*)d_out, 1024, S + 2048, 4096, S + 3072, 4096, slab3, 1024, 1024);

  // out += hole1 + hole2 + slab3
  reduce_pv<<<4096, 256, 0, stream>>>((float*)d_out, S, slab3);
}